// Round 7
// baseline (163.160 us; speedup 1.0000x reference)
//
#include <hip/hip_runtime.h>

#define DM 4096
#define NTOK 16384
#define DELTA 1e-3f
#define LIST_CAP 1024
#define LIST_OFF 16
#define ACC64_OFF (LIST_OFF + LIST_CAP * 8)   // int/float index 8208
#define WT_FLT_OFF 8320                       // byte 33280; planes occupy +1MB (ws is ~1GiB, verified r6)

typedef float f32x4 __attribute__((ext_vector_type(4)));
typedef short s16x8 __attribute__((ext_vector_type(8)));
typedef unsigned short u16x8 __attribute__((ext_vector_type(8)));

// split 8 f32 into bf16-hi (truncate) and bf16-lo (truncate of residual)
__device__ __forceinline__ void split8(const f32x4 a, const f32x4 b, s16x8& h, s16x8& l) {
#pragma unroll
  for (int j = 0; j < 8; ++j) {
    float f = (j < 4) ? a[j] : b[j - 4];
    unsigned u = __builtin_bit_cast(unsigned, f);
    float hf = __builtin_bit_cast(float, u & 0xFFFF0000u);
    float lf = f - hf;
    unsigned lu = __builtin_bit_cast(unsigned, lf);
    h[j] = (short)(u >> 16);
    l[j] = (short)(lu >> 16);
  }
}

// W(64x4096 f32) -> tiled bf16 planes: [ktile 128][eg 4][plane 2][(e&15)*64 + oct*16]
// (round-6 verified layout; B-frag read is one contiguous 1KB span per (g,plane))
__global__ __launch_bounds__(256) void prep_kernel(const float* __restrict__ W,
                                                   int* __restrict__ wsi,
                                                   float* __restrict__ wsf) {
  const int t = blockIdx.x * 256 + threadIdx.x;   // 0..8191: (e, ktile)
  const int e = t & 63, ktile = t >> 6;
  const float* src = W + (size_t)e * DM + ktile * 32;
  char* dst = (char*)wsf + WT_FLT_OFF * 4 + ktile * 8192 + (e >> 4) * 2048 + (e & 15) * 64;
#pragma unroll
  for (int c = 0; c < 4; ++c) {                   // 8 k-elems per 16B chunk
    f32x4 a = *(const f32x4*)(src + c * 8);
    f32x4 b = *(const f32x4*)(src + c * 8 + 4);
    u16x8 hv, lv;
#pragma unroll
    for (int j = 0; j < 8; ++j) {
      float f = (j < 4) ? a[j] : b[j - 4];
      unsigned u = __builtin_bit_cast(unsigned, f);
      float hf = __builtin_bit_cast(float, u & 0xFFFF0000u);
      float lf = f - hf;
      hv[j] = (unsigned short)(u >> 16);
      lv[j] = (unsigned short)(__builtin_bit_cast(unsigned, lf) >> 16);
    }
    *(u16x8*)(dst + c * 16) = hv;                 // hi plane
    *(u16x8*)(dst + 1024 + c * 16) = lv;          // lo plane
  }
  if (t == 0) wsi[0] = 0;
  if (t < 64) wsf[ACC64_OFF + t] = 0.0f;
}

// 1024 thr (16 waves) x 512 blocks = 2 blocks/CU = 32 waves/CU (HW max) @ VGPR<=64.
// wave = msub (token half) x kq (K eighth, 512 k). TLP is the latency-hiding lever
// (r6: compiler discards source-level pipelines; VGPR=60 proved loads get sunk).
__global__ __launch_bounds__(1024, 8) void router_main(const float* __restrict__ x,
                                                       float* __restrict__ out,
                                                       int* __restrict__ wsi,
                                                       float* __restrict__ wsf) {
  __shared__ float lg[32][65];
  const int tid = threadIdx.x, lane = tid & 63, w = tid >> 6;
  const int msub = w & 1;                     // token half
  const int kq = w >> 1;                      // K eighth: [512*kq, 512*kq+512)
  const int tb = blockIdx.x * 32;
  const int row16 = lane & 15, oct = lane >> 4;

  for (int i = tid; i < 32 * 65; i += 1024) (&lg[0][0])[i] = 0.0f;

  // per-lane bases (fragment conventions identical to r5/r6 verified kernels)
  const float* xp = x + (size_t)(tb + msub * 16 + row16) * DM + kq * 512 + oct * 8;
  const char* wbase = (const char*)wsf + WT_FLT_OFF * 4 + (size_t)(kq * 16) * 8192
                    + row16 * 64 + oct * 16;

  f32x4 acc[4];
#pragma unroll
  for (int g = 0; g < 4; ++g) acc[g] = (f32x4){0.f, 0.f, 0.f, 0.f};

#pragma unroll 2
  for (int T = 0; T < 16; ++T) {              // 16 x 32-k steps
    f32x4 xa = *(const f32x4*)(xp + T * 32);
    f32x4 xb = *(const f32x4*)(xp + T * 32 + 4);
    const char* wT = wbase + (size_t)T * 8192;
    s16x8 ah, al;
    split8(xa, xb, ah, al);
#pragma unroll
    for (int g = 0; g < 4; ++g) {
      s16x8 bh = *(const s16x8*)(wT + g * 2048);
      s16x8 bl = *(const s16x8*)(wT + g * 2048 + 1024);
      acc[g] = __builtin_amdgcn_mfma_f32_16x16x32_bf16(ah, bh, acc[g], 0, 0, 0);
      acc[g] = __builtin_amdgcn_mfma_f32_16x16x32_bf16(al, bh, acc[g], 0, 0, 0);
      acc[g] = __builtin_amdgcn_mfma_f32_16x16x32_bf16(ah, bl, acc[g], 0, 0, 0);
      acc[g] = __builtin_amdgcn_mfma_f32_16x16x32_bf16(al, bl, acc[g], 0, 0, 0);
    }
  }

  __syncthreads();                            // lg zeroed + all waves done
  {
    // C layout (m89): col=lane&15 (expert-in-group), row=oct*4+q (token-in-16)
    const int tt = msub * 16 + oct * 4;
#pragma unroll
    for (int g = 0; g < 4; ++g)
#pragma unroll
      for (int q = 0; q < 4; ++q)
        atomicAdd(&lg[tt + q][g * 16 + row16], acc[g][q]);  // 8 kq contributions/cell
  }
  __syncthreads();

  if (w == 0 && lane < 32) {                  // lane = token within block
    const int token = tb + lane;
    float l[64];
    float m1 = -3.4e38f, m2 = -3.4e38f, m3 = -3.4e38f, m4 = -3.4e38f;
    int i1 = 0, i2 = 0, i3 = 0, i4 = 0;
#pragma unroll
    for (int e = 0; e < 64; ++e) {            // ascending e + strict > = lax.top_k order
      float v = lg[lane][e];
      l[e] = v;
      if (v > m1)      { m4=m3;i4=i3; m3=m2;i3=i2; m2=m1;i2=i1; m1=v;i1=e; }
      else if (v > m2) { m4=m3;i4=i3; m3=m2;i3=i2; m2=v;i2=e; }
      else if (v > m3) { m4=m3;i4=i3; m3=v;i3=e; }
      else if (v > m4) { m4=v;i4=e; }
    }
    float den = 0.0f;
#pragma unroll
    for (int e = 0; e < 64; ++e) { float p = __expf(l[e] - m1); l[e] = p; den += p; }
    float rden = 1.0f / den;
#pragma unroll
    for (int e = 0; e < 64; ++e) lg[lane][e] = l[e] * rden;   // probs for aux

    float e21 = __expf(m2 - m1);
    float w1 = 1.0f / (1.0f + e21);
    float w2 = e21 * w1;
    out[2 * token + 0] = w1;
    out[2 * token + 1] = w2;
    out[32768 + 2 * token + 0] = (float)i1;
    out[32768 + 2 * token + 1] = (float)i2;

    if ((m1 - m2 < DELTA) || (m2 - m3 < DELTA)) {             // ambiguous: exact re-rank
      int idx = atomicAdd(wsi, 1);
      if (idx < LIST_CAP) {
        int* ent = wsi + LIST_OFF + idx * 8;
        ent[0] = token; ent[1] = i1; ent[2] = i2; ent[3] = i3; ent[4] = i4;
      }
    }
  }
  __syncthreads();

  if (w == 1) {                               // lane = expert: column sums over 32 tokens
    float s = 0.0f;
#pragma unroll
    for (int t = 0; t < 32; ++t) s += lg[t][lane];
    atomicAdd(&wsf[ACC64_OFF + lane], s);
  }
}

__global__ __launch_bounds__(64) void aux_kernel(const float* __restrict__ wsf,
                                                 float* __restrict__ out) {
  float m = wsf[ACC64_OFF + threadIdx.x] * (1.0f / 16384.0f);
  float v = m * m;
#pragma unroll
  for (int off = 32; off > 0; off >>= 1) v += __shfl_down(v, off);
  if (threadIdx.x == 0) out[65536] = v * 64.0f;
}

__global__ __launch_bounds__(256) void fixup_kernel(const float* __restrict__ x,
                                                    const float* __restrict__ W,
                                                    float* __restrict__ out,
                                                    const int* __restrict__ wsi) {
  int count = wsi[0]; if (count > LIST_CAP) count = LIST_CAP;
  const int wgid = blockIdx.x * 4 + (threadIdx.x >> 6);
  const int lane = threadIdx.x & 63;
  for (int idx = wgid; idx < count; idx += 64) {
    const int* ent = wsi + LIST_OFF + idx * 8;
    const int t = ent[0];
    int e[4] = {ent[1], ent[2], ent[3], ent[4]};
    float s0 = 0, s1 = 0, s2 = 0, s3 = 0;
    const f32x4* x4 = (const f32x4*)(x + (size_t)t * DM);
    const f32x4* W4 = (const f32x4*)W;
#pragma unroll 4
    for (int st = 0; st < 16; ++st) {
      f32x4 xv = x4[st * 64 + lane];
      f32x4 v0 = W4[(size_t)e[0] * 1024 + st * 64 + lane];
      f32x4 v1 = W4[(size_t)e[1] * 1024 + st * 64 + lane];
      f32x4 v2 = W4[(size_t)e[2] * 1024 + st * 64 + lane];
      f32x4 v3 = W4[(size_t)e[3] * 1024 + st * 64 + lane];
#pragma unroll
      for (int j = 0; j < 4; ++j) {
        s0 = fmaf(xv[j], v0[j], s0);
        s1 = fmaf(xv[j], v1[j], s1);
        s2 = fmaf(xv[j], v2[j], s2);
        s3 = fmaf(xv[j], v3[j], s3);
      }
    }
#pragma unroll
    for (int off = 32; off > 0; off >>= 1) {
      s0 += __shfl_down(s0, off); s1 += __shfl_down(s1, off);
      s2 += __shfl_down(s2, off); s3 += __shfl_down(s3, off);
    }
    if (lane == 0) {
      float v[4] = {s0, s1, s2, s3};
      int ord[4] = {0, 1, 2, 3};
      for (int a = 0; a < 3; ++a)
        for (int b = 0; b < 3 - a; ++b)
          if (e[ord[b]] > e[ord[b + 1]]) { int tmp = ord[b]; ord[b] = ord[b + 1]; ord[b + 1] = tmp; }
      float m1 = -3.4e38f, m2 = -3.4e38f; int i1 = -1, i2 = -1;
      for (int a = 0; a < 4; ++a) {            // ascending index + strict > = np tie-break
        float vv = v[ord[a]]; int ee = e[ord[a]];
        if (vv > m1) { m2 = m1; i2 = i1; m1 = vv; i1 = ee; }
        else if (vv > m2) { m2 = vv; i2 = ee; }
      }
      float e21 = __expf(m2 - m1);
      float w1 = 1.0f / (1.0f + e21);
      float w2 = e21 * w1;
      out[2 * t + 0] = w1;
      out[2 * t + 1] = w2;
      out[32768 + 2 * t + 0] = (float)i1;
      out[32768 + 2 * t + 1] = (float)i2;
    }
  }
}

extern "C" void kernel_launch(void* const* d_in, const int* in_sizes, int n_in,
                              void* d_out, int out_size, void* d_ws, size_t ws_size,
                              hipStream_t stream) {
  const float* x = (const float*)d_in[0];
  const float* W = (const float*)d_in[1];
  float* out = (float*)d_out;
  int* wsi = (int*)d_ws;
  float* wsf = (float*)d_ws;

  prep_kernel<<<32, 256, 0, stream>>>(W, wsi, wsf);
  router_main<<<512, 1024, 0, stream>>>(x, out, wsi, wsf);
  aux_kernel<<<1, 64, 0, stream>>>(wsf, out);
  fixup_kernel<<<16, 256, 0, stream>>>(x, W, out, wsi);
}

// Round 8
// 120.184 us; speedup vs baseline: 1.3576x; 1.3576x over previous
//
#include <hip/hip_runtime.h>

#define DM 4096
#define NTOK 16384
#define DELTA 1e-3f
#define LIST_CAP 1024
#define LIST_OFF 16
#define ACC64_OFF (LIST_OFF + LIST_CAP * 8)   // int/float index 8208
#define WT_FLT_OFF 8320                       // byte 33280; planes +1MB (ws ~1GiB, verified r6)

typedef float f32x4 __attribute__((ext_vector_type(4)));
typedef short s16x8 __attribute__((ext_vector_type(8)));
typedef unsigned short u16x8 __attribute__((ext_vector_type(8)));

typedef __attribute__((address_space(3))) char lds_char;
typedef const __attribute__((address_space(1))) char glb_char;

__device__ __forceinline__ void gload_lds16(const float* g, char* l) {
  __builtin_amdgcn_global_load_lds((glb_char*)g, (lds_char*)l, 16, 0, 0);
}

// split 8 f32 into bf16-hi (truncate) and bf16-lo (truncate of residual)
__device__ __forceinline__ void split8(const f32x4 a, const f32x4 b, s16x8& h, s16x8& l) {
#pragma unroll
  for (int j = 0; j < 8; ++j) {
    float f = (j < 4) ? a[j] : b[j - 4];
    unsigned u = __builtin_bit_cast(unsigned, f);
    float hf = __builtin_bit_cast(float, u & 0xFFFF0000u);
    float lf = f - hf;
    unsigned lu = __builtin_bit_cast(unsigned, lf);
    h[j] = (short)(u >> 16);
    l[j] = (short)(lu >> 16);
  }
}

// W(64x4096 f32) -> bf16 planes, LANE-LINEAR spans: [ktile 128][eg 4][plane 2][1KB span]
// span byte for lane(row16,oct) = oct*256 + row16*16  (== lane*16: conflict-free b128)
__global__ __launch_bounds__(256) void prep_kernel(const float* __restrict__ W,
                                                   int* __restrict__ wsi,
                                                   float* __restrict__ wsf) {
  const int t = blockIdx.x * 256 + threadIdx.x;   // 0..8191: (e, ktile)
  const int e = t & 63, ktile = t >> 6;
  const float* src = W + (size_t)e * DM + ktile * 32;
  char* dst = (char*)wsf + WT_FLT_OFF * 4 + ktile * 8192 + (e >> 4) * 2048 + (e & 15) * 16;
#pragma unroll
  for (int c = 0; c < 4; ++c) {                   // c = k-octet (oct)
    f32x4 a = *(const f32x4*)(src + c * 8);
    f32x4 b = *(const f32x4*)(src + c * 8 + 4);
    u16x8 hv, lv;
#pragma unroll
    for (int j = 0; j < 8; ++j) {
      float f = (j < 4) ? a[j] : b[j - 4];
      unsigned u = __builtin_bit_cast(unsigned, f);
      float hf = __builtin_bit_cast(float, u & 0xFFFF0000u);
      float lf = f - hf;
      hv[j] = (unsigned short)(u >> 16);
      lv[j] = (unsigned short)(__builtin_bit_cast(unsigned, lf) >> 16);
    }
    *(u16x8*)(dst + c * 256) = hv;                // hi plane
    *(u16x8*)(dst + 1024 + c * 256) = lv;         // lo plane
  }
  if (t == 0) wsi[0] = 0;
  if (t < 64) wsf[ACC64_OFF + t] = 0.0f;
}

// 512 thr x 512 blocks, 2 blocks/CU (74KB LDS), 16 waves/CU, VGPR cap 128 (no spill).
// x staged via global_load_lds into TWO static LDS buffers (m97 pattern), 32KB/stage,
// barrier per stage; W per-lane from L2 (1MB, XCD-L2-resident), lane-linear spans.
__global__ __launch_bounds__(512, 4) void router_main(const float* __restrict__ x,
                                                      float* __restrict__ out,
                                                      int* __restrict__ wsi,
                                                      float* __restrict__ wsf) {
  __shared__ char xs0[32768], xs1[32768];     // stage bufs: [tok 32][chunk 64 x16B]
  __shared__ float lg[32][65];
  const int tid = threadIdx.x, lane = tid & 63, w = tid >> 6;
  const int msub = w & 1;                     // token half
  const int kq = w >> 1;                      // stage-k quarter (64 k each)
  const int tb = blockIdx.x * 32;
  const int row16 = lane & 15, oct = lane >> 4;

  for (int i = tid; i < 32 * 65; i += 512) (&lg[0][0])[i] = 0.0f;

  // ---- staging sources: thread stages chunks f = i*512+tid, i=0..3 ----
  // chunk f: tok = f>>6, slot p = f&63 holds global chunk c = p ^ (tok&7) (m104/m173)
  const float* gs[4];
#pragma unroll
  for (int i = 0; i < 4; ++i) {
    const int f = i * 512 + tid;
    const int tok = f >> 6;
    const int c = (f & 63) ^ (tok & 7);
    gs[i] = x + (size_t)(tb + tok) * DM + c * 4;  // + s*256 per stage
  }

  const char* wtp = (const char*)wsf + WT_FLT_OFF * 4 + (size_t)lane * 16;

  f32x4 acc[4];
#pragma unroll
  for (int g = 0; g < 4; ++g) acc[g] = (f32x4){0.f, 0.f, 0.f, 0.f};

  // A-frag read: tok = msub*16+row16, stage chunk c0 = kq*16 + T*8 + oct*2 (+XOR)
  const int tokA = msub * 16 + row16;
  const int xrow = tokA * 1024;
  const int swz = tokA & 7;
  const int cA = kq * 16 + oct * 2;

#define STAGE(dst_, s_) do { \
    _Pragma("unroll") \
    for (int i_ = 0; i_ < 4; ++i_) \
      gload_lds16(gs[i_] + (s_) * 256, dst_ + i_ * 8192 + w * 1024); } while (0)

#define COMPUTE(buf_, s_) do { \
    _Pragma("unroll") \
    for (int T_ = 0; T_ < 2; ++T_) { \
      const int c0_ = cA + T_ * 8; \
      f32x4 xa_ = *(const f32x4*)(buf_ + xrow + ((c0_ ^ swz) << 4)); \
      f32x4 xb_ = *(const f32x4*)(buf_ + xrow + (((c0_ + 1) ^ swz) << 4)); \
      const char* wT_ = wtp + (size_t)((s_) * 8 + kq * 2 + T_) * 8192; \
      s16x8 ah_, al_; \
      split8(xa_, xb_, ah_, al_); \
      _Pragma("unroll") \
      for (int g_ = 0; g_ < 4; ++g_) { \
        s16x8 bh_ = *(const s16x8*)(wT_ + g_ * 2048); \
        s16x8 bl_ = *(const s16x8*)(wT_ + g_ * 2048 + 1024); \
        acc[g_] = __builtin_amdgcn_mfma_f32_16x16x32_bf16(ah_, bh_, acc[g_], 0, 0, 0); \
        acc[g_] = __builtin_amdgcn_mfma_f32_16x16x32_bf16(al_, bh_, acc[g_], 0, 0, 0); \
        acc[g_] = __builtin_amdgcn_mfma_f32_16x16x32_bf16(ah_, bl_, acc[g_], 0, 0, 0); \
        acc[g_] = __builtin_amdgcn_mfma_f32_16x16x32_bf16(al_, bl_, acc[g_], 0, 0, 0); \
      } } } while (0)

  STAGE(xs0, 0);
  __syncthreads();                            // stage 0 ready
  for (int s = 0; s < 16; s += 2) {
    if (s + 1 < 16) STAGE(xs1, s + 1);        // prefetch into the OTHER static buf
    COMPUTE(xs0, s);
    __syncthreads();                          // xs1 ready; xs0 free
    if (s + 2 < 16) STAGE(xs0, s + 2);
    COMPUTE(xs1, s + 1);
    __syncthreads();                          // xs0 ready; xs1 free
  }
#undef STAGE
#undef COMPUTE

  // ---- epilogue (identical to r3-r7 verified) ----
  {
    // C layout (m89): col=lane&15 (expert-in-group), row=oct*4+q (token-in-16)
    const int tt = msub * 16 + oct * 4;
#pragma unroll
    for (int g = 0; g < 4; ++g)
#pragma unroll
      for (int q = 0; q < 4; ++q)
        atomicAdd(&lg[tt + q][g * 16 + row16], acc[g][q]);  // 4 kq contributions/cell
  }
  __syncthreads();

  if (w == 0 && lane < 32) {                  // lane = token within block
    const int token = tb + lane;
    float l[64];
    float m1 = -3.4e38f, m2 = -3.4e38f, m3 = -3.4e38f, m4 = -3.4e38f;
    int i1 = 0, i2 = 0, i3 = 0, i4 = 0;
#pragma unroll
    for (int e = 0; e < 64; ++e) {            // ascending e + strict > = lax.top_k order
      float v = lg[lane][e];
      l[e] = v;
      if (v > m1)      { m4=m3;i4=i3; m3=m2;i3=i2; m2=m1;i2=i1; m1=v;i1=e; }
      else if (v > m2) { m4=m3;i4=i3; m3=m2;i3=i2; m2=v;i2=e; }
      else if (v > m3) { m4=m3;i4=i3; m3=v;i3=e; }
      else if (v > m4) { m4=v;i4=e; }
    }
    float den = 0.0f;
#pragma unroll
    for (int e = 0; e < 64; ++e) { float p = __expf(l[e] - m1); l[e] = p; den += p; }
    float rden = 1.0f / den;
#pragma unroll
    for (int e = 0; e < 64; ++e) lg[lane][e] = l[e] * rden;   // probs for aux

    float e21 = __expf(m2 - m1);
    float w1 = 1.0f / (1.0f + e21);
    float w2 = e21 * w1;
    out[2 * token + 0] = w1;
    out[2 * token + 1] = w2;
    out[32768 + 2 * token + 0] = (float)i1;
    out[32768 + 2 * token + 1] = (float)i2;

    if ((m1 - m2 < DELTA) || (m2 - m3 < DELTA)) {             // ambiguous: exact re-rank
      int idx = atomicAdd(wsi, 1);
      if (idx < LIST_CAP) {
        int* ent = wsi + LIST_OFF + idx * 8;
        ent[0] = token; ent[1] = i1; ent[2] = i2; ent[3] = i3; ent[4] = i4;
      }
    }
  }
  __syncthreads();

  if (w == 1) {                               // lane = expert: column sums over 32 tokens
    float s = 0.0f;
#pragma unroll
    for (int t = 0; t < 32; ++t) s += lg[t][lane];
    atomicAdd(&wsf[ACC64_OFF + lane], s);
  }
}

__global__ __launch_bounds__(64) void aux_kernel(const float* __restrict__ wsf,
                                                 float* __restrict__ out) {
  float m = wsf[ACC64_OFF + threadIdx.x] * (1.0f / 16384.0f);
  float v = m * m;
#pragma unroll
  for (int off = 32; off > 0; off >>= 1) v += __shfl_down(v, off);
  if (threadIdx.x == 0) out[65536] = v * 64.0f;
}

__global__ __launch_bounds__(256) void fixup_kernel(const float* __restrict__ x,
                                                    const float* __restrict__ W,
                                                    float* __restrict__ out,
                                                    const int* __restrict__ wsi) {
  int count = wsi[0]; if (count > LIST_CAP) count = LIST_CAP;
  const int wgid = blockIdx.x * 4 + (threadIdx.x >> 6);
  const int lane = threadIdx.x & 63;
  for (int idx = wgid; idx < count; idx += 64) {
    const int* ent = wsi + LIST_OFF + idx * 8;
    const int t = ent[0];
    int e[4] = {ent[1], ent[2], ent[3], ent[4]};
    float s0 = 0, s1 = 0, s2 = 0, s3 = 0;
    const f32x4* x4 = (const f32x4*)(x + (size_t)t * DM);
    const f32x4* W4 = (const f32x4*)W;
#pragma unroll 4
    for (int st = 0; st < 16; ++st) {
      f32x4 xv = x4[st * 64 + lane];
      f32x4 v0 = W4[(size_t)e[0] * 1024 + st * 64 + lane];
      f32x4 v1 = W4[(size_t)e[1] * 1024 + st * 64 + lane];
      f32x4 v2 = W4[(size_t)e[2] * 1024 + st * 64 + lane];
      f32x4 v3 = W4[(size_t)e[3] * 1024 + st * 64 + lane];
#pragma unroll
      for (int j = 0; j < 4; ++j) {
        s0 = fmaf(xv[j], v0[j], s0);
        s1 = fmaf(xv[j], v1[j], s1);
        s2 = fmaf(xv[j], v2[j], s2);
        s3 = fmaf(xv[j], v3[j], s3);
      }
    }
#pragma unroll
    for (int off = 32; off > 0; off >>= 1) {
      s0 += __shfl_down(s0, off); s1 += __shfl_down(s1, off);
      s2 += __shfl_down(s2, off); s3 += __shfl_down(s3, off);
    }
    if (lane == 0) {
      float v[4] = {s0, s1, s2, s3};
      int ord[4] = {0, 1, 2, 3};
      for (int a = 0; a < 3; ++a)
        for (int b = 0; b < 3 - a; ++b)
          if (e[ord[b]] > e[ord[b + 1]]) { int tmp = ord[b]; ord[b] = ord[b + 1]; ord[b + 1] = tmp; }
      float m1 = -3.4e38f, m2 = -3.4e38f; int i1 = -1, i2 = -1;
      for (int a = 0; a < 4; ++a) {            // ascending index + strict > = np tie-break
        float vv = v[ord[a]]; int ee = e[ord[a]];
        if (vv > m1) { m2 = m1; i2 = i1; m1 = vv; i1 = ee; }
        else if (vv > m2) { m2 = vv; i2 = ee; }
      }
      float e21 = __expf(m2 - m1);
      float w1 = 1.0f / (1.0f + e21);
      float w2 = e21 * w1;
      out[2 * t + 0] = w1;
      out[2 * t + 1] = w2;
      out[32768 + 2 * t + 0] = (float)i1;
      out[32768 + 2 * t + 1] = (float)i2;
    }
  }
}

extern "C" void kernel_launch(void* const* d_in, const int* in_sizes, int n_in,
                              void* d_out, int out_size, void* d_ws, size_t ws_size,
                              hipStream_t stream) {
  const float* x = (const float*)d_in[0];
  const float* W = (const float*)d_in[1];
  float* out = (float*)d_out;
  int* wsi = (int*)d_ws;
  float* wsf = (float*)d_ws;

  prep_kernel<<<32, 256, 0, stream>>>(W, wsi, wsf);
  router_main<<<512, 512, 0, stream>>>(x, out, wsi, wsf);
  aux_kernel<<<1, 64, 0, stream>>>(wsf, out);
  fixup_kernel<<<16, 256, 0, stream>>>(x, W, out, wsi);
}

// Round 9
// 116.338 us; speedup vs baseline: 1.4025x; 1.0331x over previous
//
#include <hip/hip_runtime.h>

#define DM 4096
#define NTOK 16384
#define DELTA 1e-3f
#define LIST_CAP 1024
#define LIST_OFF 16
#define ACC64_OFF (LIST_OFF + LIST_CAP * 8)   // int/float index 8208
#define WT_FLT_OFF 8320                       // byte 33280; planes +1MB (ws ~1GiB, verified r6)

typedef float f32x4 __attribute__((ext_vector_type(4)));
typedef short s16x8 __attribute__((ext_vector_type(8)));
typedef unsigned short u16x8 __attribute__((ext_vector_type(8)));

typedef __attribute__((address_space(3))) char lds_char;
typedef const __attribute__((address_space(1))) char glb_char;

__device__ __forceinline__ void gload_lds16(const float* g, char* l) {
  __builtin_amdgcn_global_load_lds((glb_char*)g, (lds_char*)l, 16, 0, 0);
}

// split 8 f32 into bf16-hi (truncate) and bf16-lo (truncate of residual)
__device__ __forceinline__ void split8(const f32x4 a, const f32x4 b, s16x8& h, s16x8& l) {
#pragma unroll
  for (int j = 0; j < 8; ++j) {
    float f = (j < 4) ? a[j] : b[j - 4];
    unsigned u = __builtin_bit_cast(unsigned, f);
    float hf = __builtin_bit_cast(float, u & 0xFFFF0000u);
    float lf = f - hf;
    unsigned lu = __builtin_bit_cast(unsigned, lf);
    h[j] = (short)(u >> 16);
    l[j] = (short)(lu >> 16);
  }
}

// W(64x4096 f32) -> bf16 planes, LANE-LINEAR spans: [ktile 128][eg 4][plane 2][1KB span]
// span byte for lane(row16,oct) = oct*256 + row16*16  (== lane*16: conflict-free b128)
// (r8-verified layout)
__global__ __launch_bounds__(256) void prep_kernel(const float* __restrict__ W,
                                                   int* __restrict__ wsi,
                                                   float* __restrict__ wsf) {
  const int t = blockIdx.x * 256 + threadIdx.x;   // 0..8191: (e, ktile)
  const int e = t & 63, ktile = t >> 6;
  const float* src = W + (size_t)e * DM + ktile * 32;
  char* dst = (char*)wsf + WT_FLT_OFF * 4 + ktile * 8192 + (e >> 4) * 2048 + (e & 15) * 16;
#pragma unroll
  for (int c = 0; c < 4; ++c) {                   // c = k-octet (oct)
    f32x4 a = *(const f32x4*)(src + c * 8);
    f32x4 b = *(const f32x4*)(src + c * 8 + 4);
    u16x8 hv, lv;
#pragma unroll
    for (int j = 0; j < 8; ++j) {
      float f = (j < 4) ? a[j] : b[j - 4];
      unsigned u = __builtin_bit_cast(unsigned, f);
      float hf = __builtin_bit_cast(float, u & 0xFFFF0000u);
      float lf = f - hf;
      hv[j] = (unsigned short)(u >> 16);
      lv[j] = (unsigned short)(__builtin_bit_cast(unsigned, lf) >> 16);
    }
    *(u16x8*)(dst + c * 256) = hv;                // hi plane
    *(u16x8*)(dst + 1024 + c * 256) = lv;         // lo plane
  }
  if (t == 0) wsi[0] = 0;
  if (t < 64) wsf[ACC64_OFF + t] = 0.0f;
}

// Counted-vmcnt 3-buffer pipeline (T3/T4): stage = 128k (16KB), 32 stages.
// Per iter: vmcnt(2) [stage s done, s+1 in flight] -> raw s_barrier (NO drain)
// -> issue stage s+2 -> compute stage s. 2 stages always in flight.
__global__ __launch_bounds__(512, 4) void router_main(const float* __restrict__ x,
                                                      float* __restrict__ out,
                                                      int* __restrict__ wsi,
                                                      float* __restrict__ wsf) {
  __shared__ char xs0[16384], xs1[16384], xs2[16384];  // [tok 32][chunk 32 x16B]
  __shared__ float lg[32][65];
  const int tid = threadIdx.x, lane = tid & 63, w = tid >> 6;
  const int msub = w & 1;                     // token half
  const int kq = w >> 1;                      // K quarter within a stage (32 k each)
  const int tb = blockIdx.x * 32;
  const int row16 = lane & 15, oct = lane >> 4;

  for (int i = tid; i < 32 * 65; i += 512) (&lg[0][0])[i] = 0.0f;

  // staging: thread stages chunks f = i*512+tid (i=0,1); stage row = 32 chunks (512B)
  // chunk f: tok = f>>5, slot p = f&31 holds global chunk c = p ^ (tok&7) (m104/m173)
  const int tok0 = tid >> 5, p0 = tid & 31;
  const float* gs0 = x + (size_t)(tb + tok0) * DM + (p0 ^ (tok0 & 7)) * 4;
  const float* gs1 = x + (size_t)(tb + 16 + tok0) * DM + (p0 ^ ((16 + tok0) & 7)) * 4;

  const char* wtp = (const char*)wsf + WT_FLT_OFF * 4 + (size_t)lane * 16;

  f32x4 acc[4];
#pragma unroll
  for (int g = 0; g < 4; ++g) acc[g] = (f32x4){0.f, 0.f, 0.f, 0.f};

  // A-frag read: tok = msub*16+row16, stage chunk c0 = kq*8 + oct*2 (+XOR swz)
  const int tokA = msub * 16 + row16;
  const int xrow = tokA * 512;
  const int swz = tokA & 7;
  const int cA = kq * 8 + oct * 2;

#define STAGE(SBUF_, s_) do { \
    gload_lds16(gs0 + (s_) * 128, SBUF_ + w * 1024); \
    gload_lds16(gs1 + (s_) * 128, SBUF_ + 8192 + w * 1024); } while (0)

#define COMPUTE(BUF_, s_) do { \
    f32x4 xa_ = *(const f32x4*)(BUF_ + xrow + ((cA ^ swz) << 4)); \
    f32x4 xb_ = *(const f32x4*)(BUF_ + xrow + (((cA + 1) ^ swz) << 4)); \
    const char* wT_ = wtp + (size_t)((s_) * 4 + kq) * 8192; \
    s16x8 ah_, al_; \
    split8(xa_, xb_, ah_, al_); \
    _Pragma("unroll") \
    for (int g_ = 0; g_ < 4; ++g_) { \
      s16x8 bh_ = *(const s16x8*)(wT_ + g_ * 2048); \
      s16x8 bl_ = *(const s16x8*)(wT_ + g_ * 2048 + 1024); \
      acc[g_] = __builtin_amdgcn_mfma_f32_16x16x32_bf16(ah_, bh_, acc[g_], 0, 0, 0); \
      acc[g_] = __builtin_amdgcn_mfma_f32_16x16x32_bf16(al_, bh_, acc[g_], 0, 0, 0); \
      acc[g_] = __builtin_amdgcn_mfma_f32_16x16x32_bf16(ah_, bl_, acc[g_], 0, 0, 0); \
      acc[g_] = __builtin_amdgcn_mfma_f32_16x16x32_bf16(al_, bl_, acc[g_], 0, 0, 0); \
    } } while (0)

#define ITER(s_, CBUF_, SBUF_) do { \
    asm volatile("s_waitcnt vmcnt(2)" ::: "memory"); \
    __builtin_amdgcn_s_barrier(); \
    STAGE(SBUF_, (s_) + 2); \
    COMPUTE(CBUF_, s_); } while (0)

  STAGE(xs0, 0);
  STAGE(xs1, 1);
#pragma unroll 1
  for (int sb = 0; sb < 30; sb += 3) {        // iters 0..29 all prefetch (s+2 <= 31)
    ITER(sb + 0, xs0, xs2);
    ITER(sb + 1, xs1, xs0);
    ITER(sb + 2, xs2, xs1);
  }
  // iter 30: stage 30 done (31 in flight), no prefetch
  asm volatile("s_waitcnt vmcnt(2)" ::: "memory");
  __builtin_amdgcn_s_barrier();
  COMPUTE(xs0, 30);
  // iter 31: drain
  asm volatile("s_waitcnt vmcnt(0)" ::: "memory");
  __builtin_amdgcn_s_barrier();
  COMPUTE(xs1, 31);
#undef ITER
#undef STAGE
#undef COMPUTE

  // ---- epilogue (identical to r3-r8 verified) ----
  __syncthreads();
  {
    // C layout (m89): col=lane&15 (expert-in-group), row=oct*4+q (token-in-16)
    const int tt = msub * 16 + oct * 4;
#pragma unroll
    for (int g = 0; g < 4; ++g)
#pragma unroll
      for (int q = 0; q < 4; ++q)
        atomicAdd(&lg[tt + q][g * 16 + row16], acc[g][q]);  // 4 kq contributions/cell
  }
  __syncthreads();

  if (w == 0 && lane < 32) {                  // lane = token within block
    const int token = tb + lane;
    float l[64];
    float m1 = -3.4e38f, m2 = -3.4e38f, m3 = -3.4e38f, m4 = -3.4e38f;
    int i1 = 0, i2 = 0, i3 = 0, i4 = 0;
#pragma unroll
    for (int e = 0; e < 64; ++e) {            // ascending e + strict > = lax.top_k order
      float v = lg[lane][e];
      l[e] = v;
      if (v > m1)      { m4=m3;i4=i3; m3=m2;i3=i2; m2=m1;i2=i1; m1=v;i1=e; }
      else if (v > m2) { m4=m3;i4=i3; m3=m2;i3=i2; m2=v;i2=e; }
      else if (v > m3) { m4=m3;i4=i3; m3=v;i3=e; }
      else if (v > m4) { m4=v;i4=e; }
    }
    float den = 0.0f;
#pragma unroll
    for (int e = 0; e < 64; ++e) { float p = __expf(l[e] - m1); l[e] = p; den += p; }
    float rden = 1.0f / den;
#pragma unroll
    for (int e = 0; e < 64; ++e) lg[lane][e] = l[e] * rden;   // probs for aux

    float e21 = __expf(m2 - m1);
    float w1 = 1.0f / (1.0f + e21);
    float w2 = e21 * w1;
    out[2 * token + 0] = w1;
    out[2 * token + 1] = w2;
    out[32768 + 2 * token + 0] = (float)i1;
    out[32768 + 2 * token + 1] = (float)i2;

    if ((m1 - m2 < DELTA) || (m2 - m3 < DELTA)) {             // ambiguous: exact re-rank
      int idx = atomicAdd(wsi, 1);
      if (idx < LIST_CAP) {
        int* ent = wsi + LIST_OFF + idx * 8;
        ent[0] = token; ent[1] = i1; ent[2] = i2; ent[3] = i3; ent[4] = i4;
      }
    }
  }
  __syncthreads();

  if (w == 1) {                               // lane = expert: column sums over 32 tokens
    float s = 0.0f;
#pragma unroll
    for (int t = 0; t < 32; ++t) s += lg[t][lane];
    atomicAdd(&wsf[ACC64_OFF + lane], s);
  }
}

__global__ __launch_bounds__(64) void aux_kernel(const float* __restrict__ wsf,
                                                 float* __restrict__ out) {
  float m = wsf[ACC64_OFF + threadIdx.x] * (1.0f / 16384.0f);
  float v = m * m;
#pragma unroll
  for (int off = 32; off > 0; off >>= 1) v += __shfl_down(v, off);
  if (threadIdx.x == 0) out[65536] = v * 64.0f;
}

__global__ __launch_bounds__(256) void fixup_kernel(const float* __restrict__ x,
                                                    const float* __restrict__ W,
                                                    float* __restrict__ out,
                                                    const int* __restrict__ wsi) {
  int count = wsi[0]; if (count > LIST_CAP) count = LIST_CAP;
  const int wgid = blockIdx.x * 4 + (threadIdx.x >> 6);
  const int lane = threadIdx.x & 63;
  for (int idx = wgid; idx < count; idx += 64) {
    const int* ent = wsi + LIST_OFF + idx * 8;
    const int t = ent[0];
    int e[4] = {ent[1], ent[2], ent[3], ent[4]};
    float s0 = 0, s1 = 0, s2 = 0, s3 = 0;
    const f32x4* x4 = (const f32x4*)(x + (size_t)t * DM);
    const f32x4* W4 = (const f32x4*)W;
#pragma unroll 4
    for (int st = 0; st < 16; ++st) {
      f32x4 xv = x4[st * 64 + lane];
      f32x4 v0 = W4[(size_t)e[0] * 1024 + st * 64 + lane];
      f32x4 v1 = W4[(size_t)e[1] * 1024 + st * 64 + lane];
      f32x4 v2 = W4[(size_t)e[2] * 1024 + st * 64 + lane];
      f32x4 v3 = W4[(size_t)e[3] * 1024 + st * 64 + lane];
#pragma unroll
      for (int j = 0; j < 4; ++j) {
        s0 = fmaf(xv[j], v0[j], s0);
        s1 = fmaf(xv[j], v1[j], s1);
        s2 = fmaf(xv[j], v2[j], s2);
        s3 = fmaf(xv[j], v3[j], s3);
      }
    }
#pragma unroll
    for (int off = 32; off > 0; off >>= 1) {
      s0 += __shfl_down(s0, off); s1 += __shfl_down(s1, off);
      s2 += __shfl_down(s2, off); s3 += __shfl_down(s3, off);
    }
    if (lane == 0) {
      float v[4] = {s0, s1, s2, s3};
      int ord[4] = {0, 1, 2, 3};
      for (int a = 0; a < 3; ++a)
        for (int b = 0; b < 3 - a; ++b)
          if (e[ord[b]] > e[ord[b + 1]]) { int tmp = ord[b]; ord[b] = ord[b + 1]; ord[b + 1] = tmp; }
      float m1 = -3.4e38f, m2 = -3.4e38f; int i1 = -1, i2 = -1;
      for (int a = 0; a < 4; ++a) {            // ascending index + strict > = np tie-break
        float vv = v[ord[a]]; int ee = e[ord[a]];
        if (vv > m1) { m2 = m1; i2 = i1; m1 = vv; i1 = ee; }
        else if (vv > m2) { m2 = vv; i2 = ee; }
      }
      float e21 = __expf(m2 - m1);
      float w1 = 1.0f / (1.0f + e21);
      float w2 = e21 * w1;
      out[2 * t + 0] = w1;
      out[2 * t + 1] = w2;
      out[32768 + 2 * t + 0] = (float)i1;
      out[32768 + 2 * t + 1] = (float)i2;
    }
  }
}

extern "C" void kernel_launch(void* const* d_in, const int* in_sizes, int n_in,
                              void* d_out, int out_size, void* d_ws, size_t ws_size,
                              hipStream_t stream) {
  const float* x = (const float*)d_in[0];
  const float* W = (const float*)d_in[1];
  float* out = (float*)d_out;
  int* wsi = (int*)d_ws;
  float* wsf = (float*)d_ws;

  prep_kernel<<<32, 256, 0, stream>>>(W, wsi, wsf);
  router_main<<<512, 512, 0, stream>>>(x, out, wsi, wsf);
  aux_kernel<<<1, 64, 0, stream>>>(wsf, out);
  fixup_kernel<<<16, 256, 0, stream>>>(x, W, out, wsi);
}

// Round 10
// 108.529 us; speedup vs baseline: 1.5034x; 1.0720x over previous
//
#include <hip/hip_runtime.h>

#define DM 4096
#define NTOK 16384
#define DELTA 1e-3f
#define LIST_CAP 1024
#define LIST_OFF 16
#define ACC64_OFF (LIST_OFF + LIST_CAP * 8)   // int/float index 8208
#define WT_FLT_OFF 8320                       // byte 33280; planes +1MB (ws ~1GiB, verified r6)

typedef float f32x4 __attribute__((ext_vector_type(4)));
typedef short s16x8 __attribute__((ext_vector_type(8)));
typedef unsigned short u16x8 __attribute__((ext_vector_type(8)));

typedef __attribute__((address_space(3))) char lds_char;
typedef const __attribute__((address_space(1))) char glb_char;

__device__ __forceinline__ void gload16(const char* g, char* l) {
  __builtin_amdgcn_global_load_lds((glb_char*)g, (lds_char*)l, 16, 0, 0);
}

// split 8 f32 into bf16-hi (truncate) and bf16-lo (truncate of residual)
__device__ __forceinline__ void split8(const f32x4 a, const f32x4 b, s16x8& h, s16x8& l) {
#pragma unroll
  for (int j = 0; j < 8; ++j) {
    float f = (j < 4) ? a[j] : b[j - 4];
    unsigned u = __builtin_bit_cast(unsigned, f);
    float hf = __builtin_bit_cast(float, u & 0xFFFF0000u);
    float lf = f - hf;
    unsigned lu = __builtin_bit_cast(unsigned, lf);
    h[j] = (short)(u >> 16);
    l[j] = (short)(lu >> 16);
  }
}

// W(64x4096 f32) -> bf16 planes (r8-verified layout), stage-linear:
// stage s (64k) = bytes [s*16384..): [ktile2][eg4][plane2][1KB span], span byte = lane*16
__global__ __launch_bounds__(256) void prep_kernel(const float* __restrict__ W,
                                                   int* __restrict__ wsi,
                                                   float* __restrict__ wsf) {
  const int t = blockIdx.x * 256 + threadIdx.x;   // 0..8191: (e, ktile)
  const int e = t & 63, ktile = t >> 6;
  const float* src = W + (size_t)e * DM + ktile * 32;
  char* dst = (char*)wsf + WT_FLT_OFF * 4 + ktile * 8192 + (e >> 4) * 2048 + (e & 15) * 16;
#pragma unroll
  for (int c = 0; c < 4; ++c) {                   // c = k-octet (oct)
    f32x4 a = *(const f32x4*)(src + c * 8);
    f32x4 b = *(const f32x4*)(src + c * 8 + 4);
    u16x8 hv, lv;
#pragma unroll
    for (int j = 0; j < 8; ++j) {
      float f = (j < 4) ? a[j] : b[j - 4];
      unsigned u = __builtin_bit_cast(unsigned, f);
      float hf = __builtin_bit_cast(float, u & 0xFFFF0000u);
      float lf = f - hf;
      hv[j] = (unsigned short)(u >> 16);
      lv[j] = (unsigned short)(__builtin_bit_cast(unsigned, lf) >> 16);
    }
    *(u16x8*)(dst + c * 256) = hv;                // hi plane
    *(u16x8*)(dst + 1024 + c * 256) = lv;         // lo plane
  }
  if (t == 0) wsi[0] = 0;
  if (t < 64) wsf[ACC64_OFF + t] = 0.0f;
}

// Both x AND W staged via global_load_lds so vmcnt counts ONLY staging loads
// (r9 lesson: per-lane W global loads entangle in the in-order vmcnt queue and
// force every prefetch to drain -> depth-0). 64 stages of 64k; x 4-buf (depth 2),
// W 2-buf (depth 1); per iter: vmcnt(1) -> raw s_barrier -> issue W(s+1),x(s+3)
// -> compute(s) from LDS. Issue-after-barrier = race-free buffer reuse.
__global__ __launch_bounds__(512, 4) void router_main(const float* __restrict__ x,
                                                      float* __restrict__ out,
                                                      int* __restrict__ wsi,
                                                      float* __restrict__ wsf) {
  __shared__ char xs0[8192], xs1[8192], xs2[8192], xs3[8192];   // [tok32][chunk16 x16B]
  __shared__ char wt0[16384], wt1[16384];                       // stage image of W planes
  __shared__ float lg[32][65];
  const int tid = threadIdx.x, lane = tid & 63, w = tid >> 6;
  const int msub = w & 1;                     // token half
  const int kq = (w >> 1) & 1;                // k half within stage (32k)
  const int egs = w >> 2;                     // expert half (32 experts)
  const int tb = blockIdx.x * 32;
  const int row16 = lane & 15, oct = lane >> 4;

  for (int i = tid; i < 32 * 65; i += 512) (&lg[0][0])[i] = 0.0f;

  // x staging: thread stages chunk tid: tok = tid>>4, slot p = tid&15 holds
  // global chunk c = p ^ (tok&7)  (pre-swizzled source, linear dest; m104/m173)
  const int tok0 = tid >> 4;
  const char* gx = (const char*)(x + (size_t)(tb + tok0) * DM
                                 + ((tid & 15) ^ (tok0 & 7)) * 4);
  // W staging: pure linear copy of the 16KB stage block; 2 chunks/thread
  const char* wpl = (const char*)wsf + WT_FLT_OFF * 4;
  const char* wq0 = wpl + tid * 16;
  const char* wq1 = wpl + 8192 + tid * 16;
  char* const ldsx = (char*)0 + w * 1024;     // wave-uniform dest offsets
  (void)ldsx;

  f32x4 acc[2];
  acc[0] = (f32x4){0.f, 0.f, 0.f, 0.f};
  acc[1] = (f32x4){0.f, 0.f, 0.f, 0.f};

  // A-frag: token tokA, k = kq*32 + oct*8 -> chunks cA, cA+1 (XOR swizzled)
  const int tokA = msub * 16 + row16;
  const int swz = tokA & 7;
  const int cA = kq * 8 + oct * 2;
  const int xoff0 = tokA * 256 + ((cA ^ swz) << 4);
  const int xoff1 = tokA * 256 + (((cA + 1) ^ swz) << 4);
  // B-frag: span base for (ktile=kq, geff=egs*2+g, plane)
  const int woff = kq * 8192 + egs * 4096 + lane * 16;

#define STAGEX(XB_, s_) gload16(gx + (size_t)(s_) * 256, XB_ + w * 1024)
#define STAGEW(WB_, s_) do { \
    gload16(wq0 + (size_t)(s_) * 16384, WB_ + w * 1024); \
    gload16(wq1 + (size_t)(s_) * 16384, WB_ + 8192 + w * 1024); } while (0)

#define COMPUTE(XB_, WB_) do { \
    f32x4 xa_ = *(const f32x4*)(XB_ + xoff0); \
    f32x4 xb_ = *(const f32x4*)(XB_ + xoff1); \
    s16x8 ah_, al_; \
    split8(xa_, xb_, ah_, al_); \
    _Pragma("unroll") \
    for (int g_ = 0; g_ < 2; ++g_) { \
      s16x8 bh_ = *(const s16x8*)(WB_ + woff + g_ * 2048); \
      s16x8 bl_ = *(const s16x8*)(WB_ + woff + g_ * 2048 + 1024); \
      acc[g_] = __builtin_amdgcn_mfma_f32_16x16x32_bf16(ah_, bh_, acc[g_], 0, 0, 0); \
      acc[g_] = __builtin_amdgcn_mfma_f32_16x16x32_bf16(al_, bh_, acc[g_], 0, 0, 0); \
      acc[g_] = __builtin_amdgcn_mfma_f32_16x16x32_bf16(ah_, bl_, acc[g_], 0, 0, 0); \
      acc[g_] = __builtin_amdgcn_mfma_f32_16x16x32_bf16(al_, bl_, acc[g_], 0, 0, 0); \
    } } while (0)

#define ITERF(vm_, s_, XC_, WC_, XS_, WS_) do { \
    asm volatile("s_waitcnt vmcnt(" #vm_ ")" ::: "memory"); \
    __builtin_amdgcn_s_barrier(); \
    STAGEW(WS_, (s_) + 1); \
    STAGEX(XS_, (s_) + 3); \
    COMPUTE(XC_, WC_); } while (0)

  // prologue: W(0), x(0), x(1), x(2)  (this order makes ITER(0)'s vmcnt(2) exact)
  STAGEW(wt0, 0);
  STAGEX(xs0, 0);
  STAGEX(xs1, 1);
  STAGEX(xs2, 2);

  ITERF(2, 0, xs0, wt0, xs3, wt1);
  ITERF(1, 1, xs1, wt1, xs0, wt0);
  ITERF(1, 2, xs2, wt0, xs1, wt1);
  ITERF(1, 3, xs3, wt1, xs2, wt0);
#pragma unroll 1
  for (int sb = 4; sb <= 56; sb += 4) {       // s = 4..59
    ITERF(1, sb + 0, xs0, wt0, xs3, wt1);
    ITERF(1, sb + 1, xs1, wt1, xs0, wt0);
    ITERF(1, sb + 2, xs2, wt0, xs1, wt1);
    ITERF(1, sb + 3, xs3, wt1, xs2, wt0);
  }
  ITERF(1, 60, xs0, wt0, xs3, wt1);           // s=60: last full iter
  // s=61: W-only prefetch
  asm volatile("s_waitcnt vmcnt(1)" ::: "memory");
  __builtin_amdgcn_s_barrier();
  STAGEW(wt0, 62);
  COMPUTE(xs1, wt1);
  // s=62: W-only prefetch, drain x
  asm volatile("s_waitcnt vmcnt(0)" ::: "memory");
  __builtin_amdgcn_s_barrier();
  STAGEW(wt1, 63);
  COMPUTE(xs2, wt0);
  // s=63: drain
  asm volatile("s_waitcnt vmcnt(0)" ::: "memory");
  __builtin_amdgcn_s_barrier();
  COMPUTE(xs3, wt1);
#undef ITERF
#undef STAGEX
#undef STAGEW
#undef COMPUTE

  // ---- epilogue (identical to r3-r9 verified) ----
  __syncthreads();
  {
    // C layout (m89): col=lane&15 (expert-in-group), row=oct*4+q (token-in-16)
    const int tt = msub * 16 + oct * 4;
#pragma unroll
    for (int g = 0; g < 2; ++g)
#pragma unroll
      for (int q = 0; q < 4; ++q)
        atomicAdd(&lg[tt + q][(egs * 2 + g) * 16 + row16], acc[g][q]);  // 2 kq adds/cell
  }
  __syncthreads();

  if (w == 0 && lane < 32) {                  // lane = token within block
    const int token = tb + lane;
    float l[64];
    float m1 = -3.4e38f, m2 = -3.4e38f, m3 = -3.4e38f, m4 = -3.4e38f;
    int i1 = 0, i2 = 0, i3 = 0, i4 = 0;
#pragma unroll
    for (int e = 0; e < 64; ++e) {            // ascending e + strict > = lax.top_k order
      float v = lg[lane][e];
      l[e] = v;
      if (v > m1)      { m4=m3;i4=i3; m3=m2;i3=i2; m2=m1;i2=i1; m1=v;i1=e; }
      else if (v > m2) { m4=m3;i4=i3; m3=m2;i3=i2; m2=v;i2=e; }
      else if (v > m3) { m4=m3;i4=i3; m3=v;i3=e; }
      else if (v > m4) { m4=v;i4=e; }
    }
    float den = 0.0f;
#pragma unroll
    for (int e = 0; e < 64; ++e) { float p = __expf(l[e] - m1); l[e] = p; den += p; }
    float rden = 1.0f / den;
#pragma unroll
    for (int e = 0; e < 64; ++e) lg[lane][e] = l[e] * rden;   // probs for aux

    float e21 = __expf(m2 - m1);
    float w1 = 1.0f / (1.0f + e21);
    float w2 = e21 * w1;
    out[2 * token + 0] = w1;
    out[2 * token + 1] = w2;
    out[32768 + 2 * token + 0] = (float)i1;
    out[32768 + 2 * token + 1] = (float)i2;

    if ((m1 - m2 < DELTA) || (m2 - m3 < DELTA)) {             // ambiguous: exact re-rank
      int idx = atomicAdd(wsi, 1);
      if (idx < LIST_CAP) {
        int* ent = wsi + LIST_OFF + idx * 8;
        ent[0] = token; ent[1] = i1; ent[2] = i2; ent[3] = i3; ent[4] = i4;
      }
    }
  }
  __syncthreads();

  if (w == 1) {                               // lane = expert: column sums over 32 tokens
    float s = 0.0f;
#pragma unroll
    for (int t = 0; t < 32; ++t) s += lg[t][lane];
    atomicAdd(&wsf[ACC64_OFF + lane], s);
  }
}

__global__ __launch_bounds__(64) void aux_kernel(const float* __restrict__ wsf,
                                                 float* __restrict__ out) {
  float m = wsf[ACC64_OFF + threadIdx.x] * (1.0f / 16384.0f);
  float v = m * m;
#pragma unroll
  for (int off = 32; off > 0; off >>= 1) v += __shfl_down(v, off);
  if (threadIdx.x == 0) out[65536] = v * 64.0f;
}

__global__ __launch_bounds__(256) void fixup_kernel(const float* __restrict__ x,
                                                    const float* __restrict__ W,
                                                    float* __restrict__ out,
                                                    const int* __restrict__ wsi) {
  int count = wsi[0]; if (count > LIST_CAP) count = LIST_CAP;
  const int wgid = blockIdx.x * 4 + (threadIdx.x >> 6);
  const int lane = threadIdx.x & 63;
  for (int idx = wgid; idx < count; idx += 64) {
    const int* ent = wsi + LIST_OFF + idx * 8;
    const int t = ent[0];
    int e[4] = {ent[1], ent[2], ent[3], ent[4]};
    float s0 = 0, s1 = 0, s2 = 0, s3 = 0;
    const f32x4* x4 = (const f32x4*)(x + (size_t)t * DM);
    const f32x4* W4 = (const f32x4*)W;
#pragma unroll 4
    for (int st = 0; st < 16; ++st) {
      f32x4 xv = x4[st * 64 + lane];
      f32x4 v0 = W4[(size_t)e[0] * 1024 + st * 64 + lane];
      f32x4 v1 = W4[(size_t)e[1] * 1024 + st * 64 + lane];
      f32x4 v2 = W4[(size_t)e[2] * 1024 + st * 64 + lane];
      f32x4 v3 = W4[(size_t)e[3] * 1024 + st * 64 + lane];
#pragma unroll
      for (int j = 0; j < 4; ++j) {
        s0 = fmaf(xv[j], v0[j], s0);
        s1 = fmaf(xv[j], v1[j], s1);
        s2 = fmaf(xv[j], v2[j], s2);
        s3 = fmaf(xv[j], v3[j], s3);
      }
    }
#pragma unroll
    for (int off = 32; off > 0; off >>= 1) {
      s0 += __shfl_down(s0, off); s1 += __shfl_down(s1, off);
      s2 += __shfl_down(s2, off); s3 += __shfl_down(s3, off);
    }
    if (lane == 0) {
      float v[4] = {s0, s1, s2, s3};
      int ord[4] = {0, 1, 2, 3};
      for (int a = 0; a < 3; ++a)
        for (int b = 0; b < 3 - a; ++b)
          if (e[ord[b]] > e[ord[b + 1]]) { int tmp = ord[b]; ord[b] = ord[b + 1]; ord[b + 1] = tmp; }
      float m1 = -3.4e38f, m2 = -3.4e38f; int i1 = -1, i2 = -1;
      for (int a = 0; a < 4; ++a) {            // ascending index + strict > = np tie-break
        float vv = v[ord[a]]; int ee = e[ord[a]];
        if (vv > m1) { m2 = m1; i2 = i1; m1 = vv; i1 = ee; }
        else if (vv > m2) { m2 = vv; i2 = ee; }
      }
      float e21 = __expf(m2 - m1);
      float w1 = 1.0f / (1.0f + e21);
      float w2 = e21 * w1;
      out[2 * t + 0] = w1;
      out[2 * t + 1] = w2;
      out[32768 + 2 * t + 0] = (float)i1;
      out[32768 + 2 * t + 1] = (float)i2;
    }
  }
}

extern "C" void kernel_launch(void* const* d_in, const int* in_sizes, int n_in,
                              void* d_out, int out_size, void* d_ws, size_t ws_size,
                              hipStream_t stream) {
  const float* x = (const float*)d_in[0];
  const float* W = (const float*)d_in[1];
  float* out = (float*)d_out;
  int* wsi = (int*)d_ws;
  float* wsf = (float*)d_ws;

  prep_kernel<<<32, 256, 0, stream>>>(W, wsi, wsf);
  router_main<<<512, 512, 0, stream>>>(x, out, wsi, wsf);
  aux_kernel<<<1, 64, 0, stream>>>(wsf, out);
  fixup_kernel<<<16, 256, 0, stream>>>(x, W, out, wsi);
}

// Round 11
// 98.933 us; speedup vs baseline: 1.6492x; 1.0970x over previous
//
#include <hip/hip_runtime.h>

#define DM 4096
#define NTOK 16384
#define DELTA 1e-3f
#define LIST_CAP 1024
#define LIST_OFF 16
#define ACC64_OFF (LIST_OFF + LIST_CAP * 8)   // int/float index 8208
#define WT_FLT_OFF 8320                       // byte 33280; planes +1MB (ws ~1GiB, verified r6)

typedef float f32x4 __attribute__((ext_vector_type(4)));
typedef short s16x8 __attribute__((ext_vector_type(8)));
typedef unsigned short u16x8 __attribute__((ext_vector_type(8)));

typedef __attribute__((address_space(3))) char lds_char;
typedef const __attribute__((address_space(1))) char glb_char;

__device__ __forceinline__ void gload16(const char* g, char* l) {
  __builtin_amdgcn_global_load_lds((glb_char*)g, (lds_char*)l, 16, 0, 0);
}

// split 8 f32 into bf16-hi (truncate) and bf16-lo (truncate of residual)
__device__ __forceinline__ void split8(const f32x4 a, const f32x4 b, s16x8& h, s16x8& l) {
#pragma unroll
  for (int j = 0; j < 8; ++j) {
    float f = (j < 4) ? a[j] : b[j - 4];
    unsigned u = __builtin_bit_cast(unsigned, f);
    float hf = __builtin_bit_cast(float, u & 0xFFFF0000u);
    float lf = f - hf;
    unsigned lu = __builtin_bit_cast(unsigned, lf);
    h[j] = (short)(u >> 16);
    l[j] = (short)(lu >> 16);
  }
}

// W(64x4096 f32) -> bf16 planes (r8-verified layout), stage-linear:
// stage s (64k) = bytes [s*16384..): [ktile2][eg4][plane2][1KB span], span byte = lane*16
__global__ __launch_bounds__(256) void prep_kernel(const float* __restrict__ W,
                                                   int* __restrict__ wsi,
                                                   float* __restrict__ wsf) {
  const int t = blockIdx.x * 256 + threadIdx.x;   // 0..8191: (e, ktile)
  const int e = t & 63, ktile = t >> 6;
  const float* src = W + (size_t)e * DM + ktile * 32;
  char* dst = (char*)wsf + WT_FLT_OFF * 4 + ktile * 8192 + (e >> 4) * 2048 + (e & 15) * 16;
#pragma unroll
  for (int c = 0; c < 4; ++c) {                   // c = k-octet (oct)
    f32x4 a = *(const f32x4*)(src + c * 8);
    f32x4 b = *(const f32x4*)(src + c * 8 + 4);
    u16x8 hv, lv;
#pragma unroll
    for (int j = 0; j < 8; ++j) {
      float f = (j < 4) ? a[j] : b[j - 4];
      unsigned u = __builtin_bit_cast(unsigned, f);
      float hf = __builtin_bit_cast(float, u & 0xFFFF0000u);
      float lf = f - hf;
      hv[j] = (unsigned short)(u >> 16);
      lv[j] = (unsigned short)(__builtin_bit_cast(unsigned, lf) >> 16);
    }
    *(u16x8*)(dst + c * 256) = hv;                // hi plane
    *(u16x8*)(dst + 1024 + c * 256) = lv;         // lo plane
  }
  if (t == 0) wsi[0] = 0;
  if (t < 64) wsf[ACC64_OFF + t] = 0.0f;
}

// 64 tokens/block, 256 blocks (1/CU), 1024 thr (16 waves). r10-verified
// counted-vmcnt pipeline; 1 W gload + 1 x gload per thread per stage.
// Per iter: vmcnt(N) -> raw s_barrier (NO drain) -> issue W(s+1), x(s+3)
// -> compute(s) from LDS. W traffic halves vs 32-tok blocks.
__global__ __launch_bounds__(1024, 4) void router_main(const float* __restrict__ x,
                                                       float* __restrict__ out,
                                                       int* __restrict__ wsi,
                                                       float* __restrict__ wsf) {
  __shared__ char xs0[16384], xs1[16384], xs2[16384], xs3[16384]; // [tok64][chunk16 x16B]
  __shared__ char wt0[16384], wt1[16384];                         // stage image of W planes
  __shared__ float lg[64][65];
  const int tid = threadIdx.x, lane = tid & 63, w = tid >> 6;
  const int msub = w & 3;                     // token 16-group (0..3)
  const int kq = (w >> 2) & 1;                // k half within stage (32k)
  const int egs = w >> 3;                     // expert half (32 experts)
  const int tb = blockIdx.x * 64;
  const int row16 = lane & 15, oct = lane >> 4;

  for (int i = tid; i < 64 * 65; i += 1024) (&lg[0][0])[i] = 0.0f;

  // x staging: thread stages chunk tid: tok = tid>>4, slot p = tid&15 holds
  // global chunk c = p ^ (tok&7)  (pre-swizzled source, linear dest; m104/m173)
  const int tok0 = tid >> 4;
  const char* gx = (const char*)(x + (size_t)(tb + tok0) * DM
                                 + ((tid & 15) ^ (tok0 & 7)) * 4);
  // W staging: pure linear copy of the 16KB stage block; 1 chunk/thread
  const char* wq = (const char*)wsf + WT_FLT_OFF * 4 + tid * 16;

  f32x4 acc[2];
  acc[0] = (f32x4){0.f, 0.f, 0.f, 0.f};
  acc[1] = (f32x4){0.f, 0.f, 0.f, 0.f};

  // A-frag: token tokA, k = kq*32 + oct*8 -> chunks cA, cA+1 (XOR swizzled)
  const int tokA = msub * 16 + row16;
  const int swz = tokA & 7;
  const int cA = kq * 8 + oct * 2;
  const int xoff0 = tokA * 256 + ((cA ^ swz) << 4);
  const int xoff1 = tokA * 256 + (((cA + 1) ^ swz) << 4);
  // B-frag: span base for (ktile=kq, geff=egs*2+g, plane)
  const int woff = kq * 8192 + egs * 4096 + lane * 16;

#define STAGEX(XB_, s_) gload16(gx + (size_t)(s_) * 256, XB_ + tid * 16 - lane * 16)
#define STAGEW(WB_, s_) gload16(wq + (size_t)(s_) * 16384, WB_ + w * 1024)

#define COMPUTE(XB_, WB_) do { \
    f32x4 xa_ = *(const f32x4*)(XB_ + xoff0); \
    f32x4 xb_ = *(const f32x4*)(XB_ + xoff1); \
    s16x8 ah_, al_; \
    split8(xa_, xb_, ah_, al_); \
    _Pragma("unroll") \
    for (int g_ = 0; g_ < 2; ++g_) { \
      s16x8 bh_ = *(const s16x8*)(WB_ + woff + g_ * 2048); \
      s16x8 bl_ = *(const s16x8*)(WB_ + woff + g_ * 2048 + 1024); \
      acc[g_] = __builtin_amdgcn_mfma_f32_16x16x32_bf16(ah_, bh_, acc[g_], 0, 0, 0); \
      acc[g_] = __builtin_amdgcn_mfma_f32_16x16x32_bf16(al_, bh_, acc[g_], 0, 0, 0); \
      acc[g_] = __builtin_amdgcn_mfma_f32_16x16x32_bf16(ah_, bl_, acc[g_], 0, 0, 0); \
      acc[g_] = __builtin_amdgcn_mfma_f32_16x16x32_bf16(al_, bl_, acc[g_], 0, 0, 0); \
    } } while (0)

#define ITERF(vm_, s_, XC_, WC_, XS_, WS_) do { \
    asm volatile("s_waitcnt vmcnt(" #vm_ ")" ::: "memory"); \
    __builtin_amdgcn_s_barrier(); \
    STAGEW(WS_, (s_) + 1); \
    STAGEX(XS_, (s_) + 3); \
    COMPUTE(XC_, WC_); } while (0)

  // prologue queue: [W0, x0, x1, x2]
  STAGEW(wt0, 0);
  STAGEX(xs0, 0);
  STAGEX(xs1, 1);
  STAGEX(xs2, 2);

  ITERF(2, 0, xs0, wt0, xs3, wt1);            // retire W0,x0
  ITERF(1, 1, xs1, wt1, xs0, wt0);
  ITERF(1, 2, xs2, wt0, xs1, wt1);
  ITERF(1, 3, xs3, wt1, xs2, wt0);
#pragma unroll 1
  for (int sb = 4; sb <= 56; sb += 4) {       // s = 4..59
    ITERF(1, sb + 0, xs0, wt0, xs3, wt1);
    ITERF(1, sb + 1, xs1, wt1, xs0, wt0);
    ITERF(1, sb + 2, xs2, wt0, xs1, wt1);
    ITERF(1, sb + 3, xs3, wt1, xs2, wt0);
  }
  ITERF(1, 60, xs0, wt0, xs3, wt1);           // stages W61, x63
  // s=61: W-only prefetch
  asm volatile("s_waitcnt vmcnt(1)" ::: "memory");
  __builtin_amdgcn_s_barrier();
  STAGEW(wt0, 62);
  COMPUTE(xs1, wt1);
  // s=62: W-only prefetch, drain x
  asm volatile("s_waitcnt vmcnt(0)" ::: "memory");
  __builtin_amdgcn_s_barrier();
  STAGEW(wt1, 63);
  COMPUTE(xs2, wt0);
  // s=63: drain
  asm volatile("s_waitcnt vmcnt(0)" ::: "memory");
  __builtin_amdgcn_s_barrier();
  COMPUTE(xs3, wt1);
#undef ITERF
#undef STAGEX
#undef STAGEW
#undef COMPUTE

  // ---- epilogue (conventions identical to r3-r10 verified) ----
  __syncthreads();
  {
    // C layout (m89): col=lane&15 (expert-in-group), row=oct*4+q (token-in-16)
    const int tt = msub * 16 + oct * 4;
#pragma unroll
    for (int g = 0; g < 2; ++g)
#pragma unroll
      for (int q = 0; q < 4; ++q)
        atomicAdd(&lg[tt + q][(egs * 2 + g) * 16 + row16], acc[g][q]);  // 2 kq adds/cell
  }
  __syncthreads();

  if (w == 0) {                               // lane = token within block (all 64)
    const int token = tb + lane;
    float l[64];
    float m1 = -3.4e38f, m2 = -3.4e38f, m3 = -3.4e38f, m4 = -3.4e38f;
    int i1 = 0, i2 = 0, i3 = 0, i4 = 0;
#pragma unroll
    for (int e = 0; e < 64; ++e) {            // ascending e + strict > = lax.top_k order
      float v = lg[lane][e];
      l[e] = v;
      if (v > m1)      { m4=m3;i4=i3; m3=m2;i3=i2; m2=m1;i2=i1; m1=v;i1=e; }
      else if (v > m2) { m4=m3;i4=i3; m3=m2;i3=i2; m2=v;i2=e; }
      else if (v > m3) { m4=m3;i4=i3; m3=v;i3=e; }
      else if (v > m4) { m4=v;i4=e; }
    }
    float den = 0.0f;
#pragma unroll
    for (int e = 0; e < 64; ++e) { float p = __expf(l[e] - m1); l[e] = p; den += p; }
    float rden = 1.0f / den;
#pragma unroll
    for (int e = 0; e < 64; ++e) lg[lane][e] = l[e] * rden;   // probs for aux

    float e21 = __expf(m2 - m1);
    float w1 = 1.0f / (1.0f + e21);
    float w2 = e21 * w1;
    out[2 * token + 0] = w1;
    out[2 * token + 1] = w2;
    out[32768 + 2 * token + 0] = (float)i1;
    out[32768 + 2 * token + 1] = (float)i2;

    if ((m1 - m2 < DELTA) || (m2 - m3 < DELTA)) {             // ambiguous: exact re-rank
      int idx = atomicAdd(wsi, 1);
      if (idx < LIST_CAP) {
        int* ent = wsi + LIST_OFF + idx * 8;
        ent[0] = token; ent[1] = i1; ent[2] = i2; ent[3] = i3; ent[4] = i4;
      }
    }
  }
  __syncthreads();

  if (w == 1) {                               // lane = expert: column sums over 64 tokens
    float s = 0.0f;
#pragma unroll
    for (int t = 0; t < 64; ++t) s += lg[t][lane];
    atomicAdd(&wsf[ACC64_OFF + lane], s);
  }
}

// fixup + aux fused (aux runs on block 0's first wave; router wrote acc64)
__global__ __launch_bounds__(256) void fixup_kernel(const float* __restrict__ x,
                                                    const float* __restrict__ W,
                                                    float* __restrict__ out,
                                                    const int* __restrict__ wsi,
                                                    const float* __restrict__ wsf) {
  if (blockIdx.x == 0 && threadIdx.x < 64) {
    float m = wsf[ACC64_OFF + threadIdx.x] * (1.0f / 16384.0f);
    float v = m * m;
#pragma unroll
    for (int off = 32; off > 0; off >>= 1) v += __shfl_down(v, off);
    if (threadIdx.x == 0) out[65536] = v * 64.0f;
  }
  int count = wsi[0]; if (count > LIST_CAP) count = LIST_CAP;
  const int wgid = blockIdx.x * 4 + (threadIdx.x >> 6);
  const int lane = threadIdx.x & 63;
  for (int idx = wgid; idx < count; idx += 64) {
    const int* ent = wsi + LIST_OFF + idx * 8;
    const int t = ent[0];
    int e[4] = {ent[1], ent[2], ent[3], ent[4]};
    float s0 = 0, s1 = 0, s2 = 0, s3 = 0;
    const f32x4* x4 = (const f32x4*)(x + (size_t)t * DM);
    const f32x4* W4 = (const f32x4*)W;
#pragma unroll 4
    for (int st = 0; st < 16; ++st) {
      f32x4 xv = x4[st * 64 + lane];
      f32x4 v0 = W4[(size_t)e[0] * 1024 + st * 64 + lane];
      f32x4 v1 = W4[(size_t)e[1] * 1024 + st * 64 + lane];
      f32x4 v2 = W4[(size_t)e[2] * 1024 + st * 64 + lane];
      f32x4 v3 = W4[(size_t)e[3] * 1024 + st * 64 + lane];
#pragma unroll
      for (int j = 0; j < 4; ++j) {
        s0 = fmaf(xv[j], v0[j], s0);
        s1 = fmaf(xv[j], v1[j], s1);
        s2 = fmaf(xv[j], v2[j], s2);
        s3 = fmaf(xv[j], v3[j], s3);
      }
    }
#pragma unroll
    for (int off = 32; off > 0; off >>= 1) {
      s0 += __shfl_down(s0, off); s1 += __shfl_down(s1, off);
      s2 += __shfl_down(s2, off); s3 += __shfl_down(s3, off);
    }
    if (lane == 0) {
      float v[4] = {s0, s1, s2, s3};
      int ord[4] = {0, 1, 2, 3};
      for (int a = 0; a < 3; ++a)
        for (int b = 0; b < 3 - a; ++b)
          if (e[ord[b]] > e[ord[b + 1]]) { int tmp = ord[b]; ord[b] = ord[b + 1]; ord[b + 1] = tmp; }
      float m1 = -3.4e38f, m2 = -3.4e38f; int i1 = -1, i2 = -1;
      for (int a = 0; a < 4; ++a) {            // ascending index + strict > = np tie-break
        float vv = v[ord[a]]; int ee = e[ord[a]];
        if (vv > m1) { m2 = m1; i2 = i1; m1 = vv; i1 = ee; }
        else if (vv > m2) { m2 = vv; i2 = ee; }
      }
      float e21 = __expf(m2 - m1);
      float w1 = 1.0f / (1.0f + e21);
      float w2 = e21 * w1;
      out[2 * t + 0] = w1;
      out[2 * t + 1] = w2;
      out[32768 + 2 * t + 0] = (float)i1;
      out[32768 + 2 * t + 1] = (float)i2;
    }
  }
}

extern "C" void kernel_launch(void* const* d_in, const int* in_sizes, int n_in,
                              void* d_out, int out_size, void* d_ws, size_t ws_size,
                              hipStream_t stream) {
  const float* x = (const float*)d_in[0];
  const float* W = (const float*)d_in[1];
  float* out = (float*)d_out;
  int* wsi = (int*)d_ws;
  float* wsf = (float*)d_ws;

  prep_kernel<<<32, 256, 0, stream>>>(W, wsi, wsf);
  router_main<<<256, 1024, 0, stream>>>(x, out, wsi, wsf);
  fixup_kernel<<<16, 256, 0, stream>>>(x, W, out, wsi, wsf);
}

// Round 12
// 92.378 us; speedup vs baseline: 1.7662x; 1.0710x over previous
//
#include <hip/hip_runtime.h>

#define DM 4096
#define NTOK 16384
#define DELTA 1e-3f
#define LIST_CAP 1024
#define LIST_OFF 16
#define ACC64_OFF (LIST_OFF + LIST_CAP * 8)   // int/float index 8208
#define WT_FLT_OFF 8320                       // byte 33280; planes +1MB (ws ~1GiB, verified r6)

typedef float f32x4 __attribute__((ext_vector_type(4)));
typedef short s16x8 __attribute__((ext_vector_type(8)));
typedef unsigned short u16x8 __attribute__((ext_vector_type(8)));

typedef __attribute__((address_space(3))) char lds_char;
typedef const __attribute__((address_space(1))) char glb_char;

__device__ __forceinline__ void gload16(const char* g, char* l) {
  __builtin_amdgcn_global_load_lds((glb_char*)g, (lds_char*)l, 16, 0, 0);
}

// split 8 f32 into bf16-hi (truncate) and bf16-lo (truncate of residual)
__device__ __forceinline__ void split8(const f32x4 a, const f32x4 b, s16x8& h, s16x8& l) {
#pragma unroll
  for (int j = 0; j < 8; ++j) {
    float f = (j < 4) ? a[j] : b[j - 4];
    unsigned u = __builtin_bit_cast(unsigned, f);
    float hf = __builtin_bit_cast(float, u & 0xFFFF0000u);
    float lf = f - hf;
    unsigned lu = __builtin_bit_cast(unsigned, lf);
    h[j] = (short)(u >> 16);
    l[j] = (short)(lu >> 16);
  }
}

// W(64x4096 f32) -> bf16 planes (r8-verified layout), stage-linear:
// ktile t (32k) at byte t*8192: [eg 4][plane 2][1KB span], span byte = lane*16
__global__ __launch_bounds__(256) void prep_kernel(const float* __restrict__ W,
                                                   int* __restrict__ wsi,
                                                   float* __restrict__ wsf) {
  const int t = blockIdx.x * 256 + threadIdx.x;   // 0..8191: (e, ktile)
  const int e = t & 63, ktile = t >> 6;
  const float* src = W + (size_t)e * DM + ktile * 32;
  char* dst = (char*)wsf + WT_FLT_OFF * 4 + ktile * 8192 + (e >> 4) * 2048 + (e & 15) * 16;
#pragma unroll
  for (int c = 0; c < 4; ++c) {                   // c = k-octet (oct)
    f32x4 a = *(const f32x4*)(src + c * 8);
    f32x4 b = *(const f32x4*)(src + c * 8 + 4);
    u16x8 hv, lv;
#pragma unroll
    for (int j = 0; j < 8; ++j) {
      float f = (j < 4) ? a[j] : b[j - 4];
      unsigned u = __builtin_bit_cast(unsigned, f);
      float hf = __builtin_bit_cast(float, u & 0xFFFF0000u);
      float lf = f - hf;
      hv[j] = (unsigned short)(u >> 16);
      lv[j] = (unsigned short)(__builtin_bit_cast(unsigned, lf) >> 16);
    }
    *(u16x8*)(dst + c * 256) = hv;                // hi plane
    *(u16x8*)(dst + 1024 + c * 256) = lv;         // lo plane
  }
  if (t == 0) wsi[0] = 0;
  if (t < 64) wsf[ACC64_OFF + t] = 0.0f;
}

// 64 tokens/block, 256 blocks (1/CU), 1024 thr (16 waves). Counted-vmcnt
// pipeline with 32 stages of 128k (halved barrier count vs r11): x 3x32KB,
// W 2x32KB (LDS = 160KiB exactly; lg unions into xs0 post-loop).
// Per iter: vmcnt(2) [retires W(s),x(s+1); x(s+2) stays in flight] -> raw
// s_barrier -> issue W(s+1), x(s+2) -> compute(s) from LDS.
__global__ __launch_bounds__(1024, 4) void router_main(const float* __restrict__ x,
                                                       float* __restrict__ out,
                                                       int* __restrict__ wsi,
                                                       float* __restrict__ wsf) {
  __shared__ char xs0[32768], xs1[32768], xs2[32768];  // [tok64][chunk32 x16B]
  __shared__ char wt0[32768], wt1[32768];              // stage image of W planes
  const int tid = threadIdx.x, lane = tid & 63, w = tid >> 6;
  const int msub = w & 3;                     // token 16-group (0..3)
  const int kq = (w >> 2) & 1;                // 64k half within stage
  const int egs = w >> 3;                     // expert half (32 experts)
  const int tb = blockIdx.x * 64;
  const int row16 = lane & 15, oct = lane >> 4;

  // x staging: thread stages chunks f = tid and tid+1024; tok = f>>5, slot
  // p = f&31 holds global chunk c = p ^ (tok&7) (pre-swizzled src; m104/m173)
  const int tok0 = tid >> 5, p0 = tid & 31;
  const char* gx0 = (const char*)(x + (size_t)(tb + tok0) * DM + (p0 ^ (tok0 & 7)) * 4);
  const char* gx1 = (const char*)(x + (size_t)(tb + 32 + tok0) * DM + (p0 ^ (tok0 & 7)) * 4);
  // W staging: linear copy of the 32KB stage block; 2 chunks/thread
  const char* wq0 = (const char*)wsf + WT_FLT_OFF * 4 + tid * 16;
  const char* wq1 = wq0 + 16384;

  f32x4 acc[2];
  acc[0] = (f32x4){0.f, 0.f, 0.f, 0.f};
  acc[1] = (f32x4){0.f, 0.f, 0.f, 0.f};

  // A-frag: token tokA, stage-k = kq*64 + T*32 + oct*8 -> chunks (XOR swizzled)
  const int tokA = msub * 16 + row16;
  const int swz = tokA & 7;
  const int xrow = tokA * 512;
  const int cA = kq * 16 + oct * 2;           // + T*8

#define STAGEX(XB_, s_) do { \
    gload16(gx0 + (size_t)(s_) * 512, XB_ + w * 1024); \
    gload16(gx1 + (size_t)(s_) * 512, XB_ + 16384 + w * 1024); } while (0)
#define STAGEW(WB_, s_) do { \
    gload16(wq0 + (size_t)(s_) * 32768, WB_ + w * 1024); \
    gload16(wq1 + (size_t)(s_) * 32768, WB_ + 16384 + w * 1024); } while (0)

#define COMPUTE(XB_, WB_) do { \
    _Pragma("unroll") \
    for (int T_ = 0; T_ < 2; ++T_) { \
      const int c0_ = cA + T_ * 8; \
      f32x4 xa_ = *(const f32x4*)(XB_ + xrow + ((c0_ ^ swz) << 4)); \
      f32x4 xb_ = *(const f32x4*)(XB_ + xrow + (((c0_ + 1) ^ swz) << 4)); \
      const char* wT_ = WB_ + (kq * 2 + T_) * 8192 + egs * 4096 + lane * 16; \
      s16x8 ah_, al_; \
      split8(xa_, xb_, ah_, al_); \
      _Pragma("unroll") \
      for (int g_ = 0; g_ < 2; ++g_) { \
        s16x8 bh_ = *(const s16x8*)(wT_ + g_ * 2048); \
        s16x8 bl_ = *(const s16x8*)(wT_ + g_ * 2048 + 1024); \
        acc[g_] = __builtin_amdgcn_mfma_f32_16x16x32_bf16(ah_, bh_, acc[g_], 0, 0, 0); \
        acc[g_] = __builtin_amdgcn_mfma_f32_16x16x32_bf16(al_, bh_, acc[g_], 0, 0, 0); \
        acc[g_] = __builtin_amdgcn_mfma_f32_16x16x32_bf16(ah_, bl_, acc[g_], 0, 0, 0); \
        acc[g_] = __builtin_amdgcn_mfma_f32_16x16x32_bf16(al_, bl_, acc[g_], 0, 0, 0); \
      } } } while (0)

#define ITERF(s_, XC_, WC_, XS_, WS_) do { \
    asm volatile("s_waitcnt vmcnt(2)" ::: "memory"); \
    __builtin_amdgcn_s_barrier(); \
    STAGEW(WS_, (s_) + 1); \
    STAGEX(XS_, (s_) + 2); \
    COMPUTE(XC_, WC_); } while (0)

  // prologue queue: [W0(2), x0(2), x1(2)]
  STAGEW(wt0, 0);
  STAGEX(xs0, 0);
  STAGEX(xs1, 1);

#pragma unroll 1
  for (int sb = 0; sb < 30; sb += 6) {        // s = 0..29 (LCM of 3-x and 2-W cycles)
    ITERF(sb + 0, xs0, wt0, xs2, wt1);
    ITERF(sb + 1, xs1, wt1, xs0, wt0);
    ITERF(sb + 2, xs2, wt0, xs1, wt1);
    ITERF(sb + 3, xs0, wt1, xs2, wt0);
    ITERF(sb + 4, xs1, wt0, xs0, wt1);
    ITERF(sb + 5, xs2, wt1, xs1, wt0);
  }
  // s=30: W31-only prefetch
  asm volatile("s_waitcnt vmcnt(2)" ::: "memory");
  __builtin_amdgcn_s_barrier();
  STAGEW(wt1, 31);
  COMPUTE(xs0, wt0);
  // s=31: drain
  asm volatile("s_waitcnt vmcnt(0)" ::: "memory");
  __builtin_amdgcn_s_barrier();
  COMPUTE(xs1, wt1);
#undef ITERF
#undef STAGEX
#undef STAGEW
#undef COMPUTE

  // ---- epilogue: lg unions into xs0 (free after the loop) ----
  __syncthreads();
  float (*lg)[65] = (float (*)[65])xs0;
  for (int i = tid; i < 64 * 65; i += 1024) (&lg[0][0])[i] = 0.0f;
  __syncthreads();
  {
    // C layout (m89): col=lane&15 (expert-in-group), row=oct*4+q (token-in-16)
    const int tt = msub * 16 + oct * 4;
#pragma unroll
    for (int g = 0; g < 2; ++g)
#pragma unroll
      for (int q = 0; q < 4; ++q)
        atomicAdd(&lg[tt + q][(egs * 2 + g) * 16 + row16], acc[g][q]);  // 2 kq adds/cell
  }
  __syncthreads();

  if (w == 0) {                               // lane = token within block (all 64)
    const int token = tb + lane;
    float l[64];
    float m1 = -3.4e38f, m2 = -3.4e38f, m3 = -3.4e38f, m4 = -3.4e38f;
    int i1 = 0, i2 = 0, i3 = 0, i4 = 0;
#pragma unroll
    for (int e = 0; e < 64; ++e) {            // ascending e + strict > = lax.top_k order
      float v = lg[lane][e];
      l[e] = v;
      if (v > m1)      { m4=m3;i4=i3; m3=m2;i3=i2; m2=m1;i2=i1; m1=v;i1=e; }
      else if (v > m2) { m4=m3;i4=i3; m3=m2;i3=i2; m2=v;i2=e; }
      else if (v > m3) { m4=m3;i4=i3; m3=v;i3=e; }
      else if (v > m4) { m4=v;i4=e; }
    }
    float den = 0.0f;
#pragma unroll
    for (int e = 0; e < 64; ++e) { float p = __expf(l[e] - m1); l[e] = p; den += p; }
    float rden = 1.0f / den;
#pragma unroll
    for (int e = 0; e < 64; ++e) lg[lane][e] = l[e] * rden;   // probs for aux

    float e21 = __expf(m2 - m1);
    float w1 = 1.0f / (1.0f + e21);
    float w2 = e21 * w1;
    out[2 * token + 0] = w1;
    out[2 * token + 1] = w2;
    out[32768 + 2 * token + 0] = (float)i1;
    out[32768 + 2 * token + 1] = (float)i2;

    if ((m1 - m2 < DELTA) || (m2 - m3 < DELTA)) {             // ambiguous: exact re-rank
      int idx = atomicAdd(wsi, 1);
      if (idx < LIST_CAP) {
        int* ent = wsi + LIST_OFF + idx * 8;
        ent[0] = token; ent[1] = i1; ent[2] = i2; ent[3] = i3; ent[4] = i4;
      }
    }
  }
  __syncthreads();

  if (w == 1) {                               // lane = expert: column sums over 64 tokens
    float s = 0.0f;
#pragma unroll
    for (int t = 0; t < 64; ++t) s += lg[t][lane];
    atomicAdd(&wsf[ACC64_OFF + lane], s);
  }
}

// fixup + aux fused (aux runs on block 0's first wave; router wrote acc64)
__global__ __launch_bounds__(256) void fixup_kernel(const float* __restrict__ x,
                                                    const float* __restrict__ W,
                                                    float* __restrict__ out,
                                                    const int* __restrict__ wsi,
                                                    const float* __restrict__ wsf) {
  if (blockIdx.x == 0 && threadIdx.x < 64) {
    float m = wsf[ACC64_OFF + threadIdx.x] * (1.0f / 16384.0f);
    float v = m * m;
#pragma unroll
    for (int off = 32; off > 0; off >>= 1) v += __shfl_down(v, off);
    if (threadIdx.x == 0) out[65536] = v * 64.0f;
  }
  int count = wsi[0]; if (count > LIST_CAP) count = LIST_CAP;
  const int wgid = blockIdx.x * 4 + (threadIdx.x >> 6);
  const int lane = threadIdx.x & 63;
  for (int idx = wgid; idx < count; idx += 64) {
    const int* ent = wsi + LIST_OFF + idx * 8;
    const int t = ent[0];
    int e[4] = {ent[1], ent[2], ent[3], ent[4]};
    float s0 = 0, s1 = 0, s2 = 0, s3 = 0;
    const f32x4* x4 = (const f32x4*)(x + (size_t)t * DM);
    const f32x4* W4 = (const f32x4*)W;
#pragma unroll 4
    for (int st = 0; st < 16; ++st) {
      f32x4 xv = x4[st * 64 + lane];
      f32x4 v0 = W4[(size_t)e[0] * 1024 + st * 64 + lane];
      f32x4 v1 = W4[(size_t)e[1] * 1024 + st * 64 + lane];
      f32x4 v2 = W4[(size_t)e[2] * 1024 + st * 64 + lane];
      f32x4 v3 = W4[(size_t)e[3] * 1024 + st * 64 + lane];
#pragma unroll
      for (int j = 0; j < 4; ++j) {
        s0 = fmaf(xv[j], v0[j], s0);
        s1 = fmaf(xv[j], v1[j], s1);
        s2 = fmaf(xv[j], v2[j], s2);
        s3 = fmaf(xv[j], v3[j], s3);
      }
    }
#pragma unroll
    for (int off = 32; off > 0; off >>= 1) {
      s0 += __shfl_down(s0, off); s1 += __shfl_down(s1, off);
      s2 += __shfl_down(s2, off); s3 += __shfl_down(s3, off);
    }
    if (lane == 0) {
      float v[4] = {s0, s1, s2, s3};
      int ord[4] = {0, 1, 2, 3};
      for (int a = 0; a < 3; ++a)
        for (int b = 0; b < 3 - a; ++b)
          if (e[ord[b]] > e[ord[b + 1]]) { int tmp = ord[b]; ord[b] = ord[b + 1]; ord[b + 1] = tmp; }
      float m1 = -3.4e38f, m2 = -3.4e38f; int i1 = -1, i2 = -1;
      for (int a = 0; a < 4; ++a) {            // ascending index + strict > = np tie-break
        float vv = v[ord[a]]; int ee = e[ord[a]];
        if (vv > m1) { m2 = m1; i2 = i1; m1 = vv; i1 = ee; }
        else if (vv > m2) { m2 = vv; i2 = ee; }
      }
      float e21 = __expf(m2 - m1);
      float w1 = 1.0f / (1.0f + e21);
      float w2 = e21 * w1;
      out[2 * t + 0] = w1;
      out[2 * t + 1] = w2;
      out[32768 + 2 * t + 0] = (float)i1;
      out[32768 + 2 * t + 1] = (float)i2;
    }
  }
}

extern "C" void kernel_launch(void* const* d_in, const int* in_sizes, int n_in,
                              void* d_out, int out_size, void* d_ws, size_t ws_size,
                              hipStream_t stream) {
  const float* x = (const float*)d_in[0];
  const float* W = (const float*)d_in[1];
  float* out = (float*)d_out;
  int* wsi = (int*)d_ws;
  float* wsf = (float*)d_ws;

  prep_kernel<<<32, 256, 0, stream>>>(W, wsi, wsf);
  router_main<<<256, 1024, 0, stream>>>(x, out, wsi, wsf);
  fixup_kernel<<<16, 256, 0, stream>>>(x, W, out, wsi, wsf);
}